// Round 13
// baseline (1326.637 us; speedup 1.0000x reference)
//
#include <hip/hip_runtime.h>
#include <hip/hip_bf16.h>

typedef signed char i8_t;
typedef int i32x4 __attribute__((ext_vector_type(4)));
typedef float f32x4 __attribute__((ext_vector_type(4)));

typedef const __attribute__((address_space(1))) void* gptr_t;
typedef __attribute__((address_space(3))) void* sptr_t;

#define GLD16(g, l) __builtin_amdgcn_global_load_lds((gptr_t)(g), (sptr_t)(l), 16, 0, 0)

// ---------------------------------------------------------------------------
// Kernel 1: global sum of W (fp32 partials, double atomic) -> ws scalar
// ---------------------------------------------------------------------------
__global__ void sum_w_kernel(const float* __restrict__ W, double* __restrict__ out, int n4) {
    int i = blockIdx.x * blockDim.x + threadIdx.x;
    int stride = gridDim.x * blockDim.x;
    float s = 0.f;
    for (; i < n4; i += stride) {
        float4 v = ((const float4*)W)[i];
        s += (v.x + v.y) + (v.z + v.w);
    }
    #pragma unroll
    for (int off = 32; off > 0; off >>= 1) s += __shfl_down(s, off, 64);
    __shared__ float red[4];
    int t = threadIdx.x;
    if ((t & 63) == 0) red[t >> 6] = s;
    __syncthreads();
    if (t == 0) {
        float bs = red[0] + red[1] + red[2] + red[3];
        atomicAdd(out, (double)bs);
    }
}

// ---------------------------------------------------------------------------
// Kernel 2: quantize W -> i8 {0,1}
// ---------------------------------------------------------------------------
__global__ void quant_w_kernel(const float* __restrict__ W, i8_t* __restrict__ Wq,
                               const double* __restrict__ sumw, float inv_n, int n4) {
    float mean = (float)(*sumw) * inv_n;
    int i = blockIdx.x * blockDim.x + threadIdx.x;
    int stride = gridDim.x * blockDim.x;
    for (; i < n4; i += stride) {
        float4 v = ((const float4*)W)[i];
        char4 o;
        o.x = (v.x > mean) ? 1 : 0;
        o.y = (v.y > mean) ? 1 : 0;
        o.z = (v.z > mean) ? 1 : 0;
        o.w = (v.w > mean) ? 1 : 0;
        ((char4*)Wq)[i] = o;
    }
}

// ---------------------------------------------------------------------------
// Kernel 3: per-row symmetric int8 quantization of x (one block per row).
// s_row = absmax/127; xq = rint(x/s) clamped; scale[row] = s_row.
// ---------------------------------------------------------------------------
__global__ void quant_x_kernel(const float* __restrict__ x, i8_t* __restrict__ xq,
                               float* __restrict__ scale, int K) {
    __shared__ float red[4];
    int row = blockIdx.x;
    int t = threadIdx.x;
    const float4* xr = (const float4*)(x + (size_t)row * K);

    float4 v[4];
    float am = 0.f;
    #pragma unroll
    for (int j = 0; j < 4; ++j) {
        v[j] = xr[t + j * 256];
        am = fmaxf(am, fmaxf(fmaxf(fabsf(v[j].x), fabsf(v[j].y)),
                             fmaxf(fabsf(v[j].z), fabsf(v[j].w))));
    }
    #pragma unroll
    for (int off = 32; off > 0; off >>= 1) am = fmaxf(am, __shfl_down(am, off, 64));
    if ((t & 63) == 0) red[t >> 6] = am;
    __syncthreads();
    float amax = fmaxf(fmaxf(red[0], red[1]), fmaxf(red[2], red[3]));
    amax = fmaxf(amax, 1e-20f);
    float s = amax * (1.0f / 127.0f);
    float inv = 127.0f / amax;
    if (t == 0) scale[row] = s;

    char4* oq = (char4*)(xq + (size_t)row * K);
    #pragma unroll
    for (int j = 0; j < 4; ++j) {
        char4 o;
        o.x = (i8_t)(int)rintf(fminf(fmaxf(v[j].x * inv, -127.f), 127.f));
        o.y = (i8_t)(int)rintf(fminf(fmaxf(v[j].y * inv, -127.f), 127.f));
        o.z = (i8_t)(int)rintf(fminf(fmaxf(v[j].z * inv, -127.f), 127.f));
        o.w = (i8_t)(int)rintf(fminf(fmaxf(v[j].w * inv, -127.f), 127.f));
        oq[t + j * 256] = o;
    }
}

// ---------------------------------------------------------------------------
// Kernel 4: quantize b (single block; n = 4096)
// ---------------------------------------------------------------------------
__global__ void quant_b_kernel(const float* __restrict__ b, float* __restrict__ bq, int n) {
    int t = threadIdx.x;
    float s = 0.f;
    for (int i = t; i < n; i += 256) s += b[i];
    #pragma unroll
    for (int off = 32; off > 0; off >>= 1) s += __shfl_down(s, off, 64);
    __shared__ float red[4];
    if ((t & 63) == 0) red[t >> 6] = s;
    __syncthreads();
    float mean = (red[0] + red[1] + red[2] + red[3]) / (float)n;
    for (int i = t; i < n; i += 256) bq[i] = (b[i] > mean) ? 1.0f : 0.0f;
}

// ---------------------------------------------------------------------------
// Kernel 5: INT8 MFMA GEMM, 256x256 tile, BK=64 (i8 rows = 64 B), 8 waves
// (2Mx4N), R4's 4-phase schedule. KEY CHANGE (R13): LDS halved to 64 KiB
// (2 x 32 KiB buffers) -> 2 blocks/CU co-resident. Cross-block overlap:
// when one block's waves sit at a barrier / read-burst, the other block's
// waves feed the matrix pipe (m114 mechanism; intra-block scheduling could
// never fix this at 1 block/CU, R5-R9).
// Bank behavior with 64B rows: each frag ds_read_b128 (16 rows x 64 B)
// covers exactly 1024 CONTIGUOUS bytes -> uniform 8 words/bank = wave64
// floor, zero conflicts, NO swizzle needed; staging is plain linear.
// Stages: 4 GLD16/tile issued ph1+ph2 into dead buffer; one vmcnt(0) at
// ph4-end (issue-to-wait ~2000 cyc >> 900 HBM latency -> free) + BAR.
//   C[M,N] = (float)( A_i8[M,K] * B_i8[N,K]^T )  (scale re-applied in rownorm)
// MFMA v_mfma_i32_16x16x64_i8: lane group g=(l>>4) holds k=g*16+[0,16).
// Epilogue: i32->float, coalesced LDS bounce (16-row chunks, fits 64 KiB).
// ---------------------------------------------------------------------------
#define PRIO1 __builtin_amdgcn_s_setprio(1)
#define PRIO0 __builtin_amdgcn_s_setprio(0)
#define BAR() __builtin_amdgcn_s_barrier()
#define WAITV0() asm volatile("s_waitcnt vmcnt(0)" ::: "memory")
#define UNRL _Pragma("unroll")

__global__ __launch_bounds__(512, 4) void gemm_i8_256(
        const i8_t* __restrict__ A, const i8_t* __restrict__ B,
        float* __restrict__ C, int M, int N, int K) {
    __shared__ int lds32[16384];       // 64 KiB: [buf][A 16K i8 | B 16K i8]
    char* ldsc = (char*)lds32;
    float* ldsf = (float*)lds32;       // epilogue bounce reuses the same LDS

    int nbn = N >> 8;
    int nwg = gridDim.x;
    int bid = blockIdx.x;
    int cpx = nwg >> 3;
    int wg = (bid & 7) * cpx + (bid >> 3);   // XCD swizzle (nwg % 8 == 0)
    int tm = wg / nbn, tn = wg % nbn;

    int t = threadIdx.x;
    int w = t >> 6, l = t & 63;
    int wr = w >> 2, wc = w & 3;             // 2 M-waves x 4 N-waves
    int wrOff = wr * 8192;                   // 128 rows * 64 B
    int wcOff = wc * 4096;                   // 64 rows * 64 B

    // frag-read lane offset within a 16-row x 64B frag block (contiguous 1KB)
    int laneOff = (l & 15) * 64 + (l >> 4) * 16;

    // stage-side source offsets (linear, no swizzle): instr c covers rows
    // c*128..c*128+127; thread t -> row c*128 + (t>>2), bytes (t&3)*16.
    int offA[2], offB[2];
    UNRL
    for (int c = 0; c < 2; ++c) {
        offA[c] = (c * 128 + (t >> 2)) * K + (t & 3) * 16;
        offB[c] = offA[c];
    }

    const i8_t* srcA = A + (size_t)tm * 256 * K;
    const i8_t* srcB = B + (size_t)tn * 256 * K;

    i32x4 acc[8][4] = {};
    i32x4 af[4], bf0[2], bf1[2];

#define STAGE_A(P, KIDX) do { \
    GLD16(srcA + (size_t)offA[0] + (KIDX), ldsc + (P)*32768 + w*1024); \
    GLD16(srcA + (size_t)offA[1] + (KIDX), ldsc + (P)*32768 + 8192 + w*1024); \
} while (0)
#define STAGE_B(P, KIDX) do { \
    GLD16(srcB + (size_t)offB[0] + (KIDX), ldsc + (P)*32768 + 16384 + w*1024); \
    GLD16(srcB + (size_t)offB[1] + (KIDX), ldsc + (P)*32768 + 16384 + 8192 + w*1024); \
} while (0)
// A m-half H: frags fm = H*4+f, contiguous 1KB each
#define LOAD_AF(P, H) do { UNRL for (int f = 0; f < 4; ++f) { \
    af[f] = *(const i32x4*)(ldsc + (P)*32768 + wrOff + ((H)*4+f)*1024 + laneOff); \
} } while (0)
// B n-half H: frags e' = H*2+e
#define LOAD_BF(BF, P, H) do { UNRL for (int e = 0; e < 2; ++e) { \
    BF[e] = *(const i32x4*)(ldsc + (P)*32768 + 16384 + wcOff + ((H)*2+e)*1024 + laneOff); \
} } while (0)
// Quadrant: 4 m-frags x 2 n-frags, one full-K(64) MFMA each
#define MFMA_Q(QM, QN, BF) do { UNRL for (int f = 0; f < 4; ++f) UNRL for (int e = 0; e < 2; ++e) { \
    acc[(QM)*4+f][(QN)*2+e] = __builtin_amdgcn_mfma_i32_16x16x64_i8(af[f], BF[e], acc[(QM)*4+f][(QN)*2+e], 0, 0, 0); \
} } while (0)

#define TILE(P, PN, KTN) do { \
    LOAD_AF(P, 0); LOAD_BF(bf0, P, 0); STAGE_A(PN, KTN); \
    PRIO1; MFMA_Q(0, 0, bf0); PRIO0; BAR(); \
    LOAD_BF(bf1, P, 1);                STAGE_B(PN, KTN); \
    PRIO1; MFMA_Q(0, 1, bf1); PRIO0; BAR(); \
    LOAD_AF(P, 1); \
    PRIO1; MFMA_Q(1, 1, bf1); PRIO0; BAR(); \
    PRIO1; MFMA_Q(1, 0, bf0); PRIO0; WAITV0(); BAR(); \
} while (0)

    // prologue: stage tile 0 (K bytes 0..63) into buf0, drain once
    STAGE_A(0, 0); STAGE_B(0, 0);
    WAITV0();
    BAR();

    for (int kt = 0; kt < K; kt += 128) {
        int kn1 = kt + 64;
        int kn2 = (kt + 128 < K) ? kt + 128 : 0;   // wrap: redundant, never read
        TILE(0, 1, kn1);
        TILE(1, 0, kn2);
    }

    // Coalesced epilogue (i32 -> float), 16-row chunks (8 per wave).
    // Per-wave region 16 x 68 floats (stride 272 B), base w*1088 floats
    // (8 waves x 4352 B = 34.8 KiB <= 64 KiB). Final TILE's BAR precedes.
    {
        int crowW = tm * 256 + wr * 128;
        int ccolW = tn * 256 + wc * 64;
        int lq = l >> 4, lc = l & 15;
        UNRL
        for (int fm = 0; fm < 8; ++fm) {
            UNRL
            for (int fn = 0; fn < 4; ++fn)
                UNRL
                for (int r = 0; r < 4; ++r)
                    ldsf[w * 1088 + (lq * 4 + r) * 68 + fn * 16 + lc]
                        = (float)acc[fm][fn][r];
            BAR();
            UNRL
            for (int rr = 0; rr < 4; ++rr) {
                f32x4 v = *(const f32x4*)&ldsf[w * 1088 + (rr * 4 + lq) * 68 + lc * 4];
                *(f32x4*)&C[(size_t)(crowW + fm * 16 + rr * 4 + lq) * N + (ccolW + lc * 4)] = v;
            }
            BAR();
        }
    }
}

// ---------------------------------------------------------------------------
// Kernel 6: per-row normalize in-place with row scale:
//   a = z*s_row + bq;  out = (a - mean) / (sqrt(var_ddof1) + eps)
// ---------------------------------------------------------------------------
__device__ __forceinline__ float block_sum_256(float v, float* red) {
    #pragma unroll
    for (int off = 32; off > 0; off >>= 1) v += __shfl_down(v, off, 64);
    int t = threadIdx.x;
    __syncthreads();
    if ((t & 63) == 0) red[t >> 6] = v;
    __syncthreads();
    return red[0] + red[1] + red[2] + red[3];
}

__global__ void rownorm_kernel(float* __restrict__ z, const float* __restrict__ bq,
                               const float* __restrict__ scale, int N) {
    __shared__ float red[4];
    int row = blockIdx.x;
    float* zr = z + (size_t)row * N;
    float srow = scale[row];
    int t = threadIdx.x;

    float4 v[4];
    float s = 0.f;
    #pragma unroll
    for (int j = 0; j < 4; ++j) {
        int idx = t + j * 256;
        float4 a = ((const float4*)zr)[idx];
        float4 bb = ((const float4*)bq)[idx];
        a.x = a.x * srow + bb.x; a.y = a.y * srow + bb.y;
        a.z = a.z * srow + bb.z; a.w = a.w * srow + bb.w;
        v[j] = a;
        s += (a.x + a.y) + (a.z + a.w);
    }
    float total = block_sum_256(s, red);
    float mean = total * (1.0f / 4096.0f);

    float q = 0.f;
    #pragma unroll
    for (int j = 0; j < 4; ++j) {
        float dx = v[j].x - mean, dy = v[j].y - mean, dz = v[j].z - mean, dw = v[j].w - mean;
        q += (dx * dx + dy * dy) + (dz * dz + dw * dw);
    }
    float qtot = block_sum_256(q, red);
    float var = qtot * (1.0f / 4095.0f);
    float inv = 1.0f / (sqrtf(var) + 1e-8f);

    #pragma unroll
    for (int j = 0; j < 4; ++j) {
        int idx = t + j * 256;
        float4 o;
        o.x = (v[j].x - mean) * inv;
        o.y = (v[j].y - mean) * inv;
        o.z = (v[j].z - mean) * inv;
        o.w = (v[j].w - mean) * inv;
        ((float4*)zr)[idx] = o;
    }
}

// ---------------------------------------------------------------------------
extern "C" void kernel_launch(void* const* d_in, const int* in_sizes, int n_in,
                              void* d_out, int out_size, void* d_ws, size_t ws_size,
                              hipStream_t stream) {
    const float* x = (const float*)d_in[0];
    const float* W = (const float*)d_in[1];
    const float* b = (const float*)d_in[2];
    float* out = (float*)d_out;

    const int N = in_sizes[2];            // 4096 (OUT)
    const int K = in_sizes[1] / N;        // 4096 (IN)
    const int M = in_sizes[0] / K;        // 8192

    // workspace layout
    char* ws = (char*)d_ws;
    i8_t* xq = (i8_t*)ws;                                           // M*K i8
    i8_t* wq = (i8_t*)(ws + (size_t)M * K);                         // N*K i8
    float* scales = (float*)(ws + (size_t)M * K + (size_t)N * K);   // M fp32
    float* bq = (float*)(ws + (size_t)M * K + (size_t)N * K + (size_t)M * 4);  // N fp32
    double* sumw = (double*)(ws + (size_t)M * K + (size_t)N * K + (size_t)M * 4 + (size_t)N * 4);

    hipMemsetAsync(sumw, 0, sizeof(double), stream);
    sum_w_kernel<<<1024, 256, 0, stream>>>(W, sumw, N * K / 4);
    quant_w_kernel<<<2048, 256, 0, stream>>>(W, wq, sumw, 1.0f / (float)((size_t)N * K), N * K / 4);
    quant_x_kernel<<<M, 256, 0, stream>>>(x, xq, scales, K);
    quant_b_kernel<<<1, 256, 0, stream>>>(b, bq, N);

    int grid = (M / 256) * (N / 256);
    gemm_i8_256<<<grid, 512, 0, stream>>>(xq, wq, out, M, N, K);

    rownorm_kernel<<<M, 256, 0, stream>>>(out, bq, scales, N);
}

// Round 14
// 255.101 us; speedup vs baseline: 5.2004x; 5.2004x over previous
//
#include <hip/hip_runtime.h>
#include <hip/hip_bf16.h>

typedef signed char i8_t;
typedef int i32x4 __attribute__((ext_vector_type(4)));
typedef float f32x4 __attribute__((ext_vector_type(4)));

typedef const __attribute__((address_space(1))) void* gptr_t;
typedef __attribute__((address_space(3))) void* sptr_t;

#define GLD16(g, l) __builtin_amdgcn_global_load_lds((gptr_t)(g), (sptr_t)(l), 16, 0, 0)

// ---------------------------------------------------------------------------
// Kernel 1: global sum of W (fp32 partials, double atomic) -> ws scalar
// ---------------------------------------------------------------------------
__global__ void sum_w_kernel(const float* __restrict__ W, double* __restrict__ out, int n4) {
    int i = blockIdx.x * blockDim.x + threadIdx.x;
    int stride = gridDim.x * blockDim.x;
    float s = 0.f;
    for (; i < n4; i += stride) {
        float4 v = ((const float4*)W)[i];
        s += (v.x + v.y) + (v.z + v.w);
    }
    #pragma unroll
    for (int off = 32; off > 0; off >>= 1) s += __shfl_down(s, off, 64);
    __shared__ float red[4];
    int t = threadIdx.x;
    if ((t & 63) == 0) red[t >> 6] = s;
    __syncthreads();
    if (t == 0) {
        float bs = red[0] + red[1] + red[2] + red[3];
        atomicAdd(out, (double)bs);
    }
}

// ---------------------------------------------------------------------------
// Kernel 2: quantize W -> i8 {0,1}
// ---------------------------------------------------------------------------
__global__ void quant_w_kernel(const float* __restrict__ W, i8_t* __restrict__ Wq,
                               const double* __restrict__ sumw, float inv_n, int n4) {
    float mean = (float)(*sumw) * inv_n;
    int i = blockIdx.x * blockDim.x + threadIdx.x;
    int stride = gridDim.x * blockDim.x;
    for (; i < n4; i += stride) {
        float4 v = ((const float4*)W)[i];
        char4 o;
        o.x = (v.x > mean) ? 1 : 0;
        o.y = (v.y > mean) ? 1 : 0;
        o.z = (v.z > mean) ? 1 : 0;
        o.w = (v.w > mean) ? 1 : 0;
        ((char4*)Wq)[i] = o;
    }
}

// ---------------------------------------------------------------------------
// Kernel 3: per-row symmetric int8 quantization of x (one block per row).
// ---------------------------------------------------------------------------
__global__ void quant_x_kernel(const float* __restrict__ x, i8_t* __restrict__ xq,
                               float* __restrict__ scale, int K) {
    __shared__ float red[4];
    int row = blockIdx.x;
    int t = threadIdx.x;
    const float4* xr = (const float4*)(x + (size_t)row * K);

    float4 v[4];
    float am = 0.f;
    #pragma unroll
    for (int j = 0; j < 4; ++j) {
        v[j] = xr[t + j * 256];
        am = fmaxf(am, fmaxf(fmaxf(fabsf(v[j].x), fabsf(v[j].y)),
                             fmaxf(fabsf(v[j].z), fabsf(v[j].w))));
    }
    #pragma unroll
    for (int off = 32; off > 0; off >>= 1) am = fmaxf(am, __shfl_down(am, off, 64));
    if ((t & 63) == 0) red[t >> 6] = am;
    __syncthreads();
    float amax = fmaxf(fmaxf(red[0], red[1]), fmaxf(red[2], red[3]));
    amax = fmaxf(amax, 1e-20f);
    float s = amax * (1.0f / 127.0f);
    float inv = 127.0f / amax;
    if (t == 0) scale[row] = s;

    char4* oq = (char4*)(xq + (size_t)row * K);
    #pragma unroll
    for (int j = 0; j < 4; ++j) {
        char4 o;
        o.x = (i8_t)(int)rintf(fminf(fmaxf(v[j].x * inv, -127.f), 127.f));
        o.y = (i8_t)(int)rintf(fminf(fmaxf(v[j].y * inv, -127.f), 127.f));
        o.z = (i8_t)(int)rintf(fminf(fmaxf(v[j].z * inv, -127.f), 127.f));
        o.w = (i8_t)(int)rintf(fminf(fmaxf(v[j].w * inv, -127.f), 127.f));
        oq[t + j * 256] = o;
    }
}

// ---------------------------------------------------------------------------
// Kernel 4: quantize b (single block; n = 4096)
// ---------------------------------------------------------------------------
__global__ void quant_b_kernel(const float* __restrict__ b, float* __restrict__ bq, int n) {
    int t = threadIdx.x;
    float s = 0.f;
    for (int i = t; i < n; i += 256) s += b[i];
    #pragma unroll
    for (int off = 32; off > 0; off >>= 1) s += __shfl_down(s, off, 64);
    __shared__ float red[4];
    if ((t & 63) == 0) red[t >> 6] = s;
    __syncthreads();
    float mean = (red[0] + red[1] + red[2] + red[3]) / (float)n;
    for (int i = t; i < n; i += 256) bq[i] = (b[i] > mean) ? 1.0f : 0.0f;
}

// ---------------------------------------------------------------------------
// Kernel 5: INT8 MFMA GEMM, 128x256 tile, BK=64 (i8 rows = 64 B), 8 waves
// (2Mx4N), per-wave output 64x64 -> acc = 64 AGPR; combined regs ~110 < 128
// so __launch_bounds__(512,4) is SATISFIABLE (R13 failed because 256^2 tile
// needs acc=128 alone). LDS 48 KiB -> 2 blocks/CU co-resident: one block's
// read/barrier phase overlaps the other's MFMA (m114). Simple 1-barrier tile:
//   STAGE(3 GLD16 -> dead buf) ; read 8 frags ; 16 MFMA ; vmcnt(0)+BAR.
// Bank behavior (64-B rows): swizzle addr ^= ((addr>>3)&0x30) (XOR row bits
// 1,2 into addr[5:4]); involution, row-preserving; 64 lanes spread 8-per-
// 16B-position = all-banks-busy floor. Stage source pre-swizzled:
//   col = ((t&3) ^ ((t>>3)&3)) << 4.
//   C[M,N] = (float)( A_i8[M,K] * B_i8[N,K]^T )  (scale re-applied in rownorm)
// MFMA v_mfma_i32_16x16x64_i8: lane group g=(l>>4) holds k=g*16+[0,16).
// ---------------------------------------------------------------------------
#define PRIO1 __builtin_amdgcn_s_setprio(1)
#define PRIO0 __builtin_amdgcn_s_setprio(0)
#define BAR() __builtin_amdgcn_s_barrier()
#define WAITV0() asm volatile("s_waitcnt vmcnt(0)" ::: "memory")
#define UNRL _Pragma("unroll")

__global__ __launch_bounds__(512, 4) void gemm_i8_128x256(
        const i8_t* __restrict__ A, const i8_t* __restrict__ B,
        float* __restrict__ C, int M, int N, int K) {
    __shared__ int lds32[12288];       // 48 KiB: [buf][A 8 KiB | B 16 KiB]
    char* ldsc = (char*)lds32;
    float* ldsf = (float*)lds32;       // epilogue bounce reuses the same LDS

    int nbn = N >> 8;                  // 16
    int nwg = gridDim.x;               // 1024
    int bid = blockIdx.x;
    int cpx = nwg >> 3;
    int wg = (bid & 7) * cpx + (bid >> 3);   // XCD swizzle (nwg % 8 == 0)
    int tm = wg / nbn, tn = wg % nbn;

    int t = threadIdx.x;
    int w = t >> 6, l = t & 63;
    int wr = w >> 2, wc = w & 3;             // 2 M-waves x 4 N-waves

    // frag-read lane offset: row r=l&15 (64-B rows), k-group q=l>>4,
    // swizzle ((r>>1)&3)<<4 == ((l&6)<<3)
    int laneA = ((l & 15) * 64 + (l >> 4) * 16) ^ ((l & 6) << 3);

    // stage source: thread t covers LDS-linear t*16 within its region;
    // row = t>>2, pre-swizzled col byte:
    int srow = t >> 2;                       // 0..127
    int scol = ((t & 3) ^ ((t >> 3) & 3)) << 4;

    const i8_t* srcA = A + (size_t)tm * 128 * K;
    const i8_t* srcB = B + (size_t)tn * 256 * K;
    int offA  = srow * K + scol;
    int offB0 = srow * K + scol;
    int offB1 = (128 + srow) * K + scol;

    i32x4 acc[4][4] = {};                    // per-wave 64x64: 64 AGPR
    i32x4 af[4], bf[4];

#define STAGE(P, KIDX) do { \
    GLD16(srcA + (size_t)offA  + (KIDX), ldsc + (P)*24576 + w*1024); \
    GLD16(srcB + (size_t)offB0 + (KIDX), ldsc + (P)*24576 + 8192 + w*1024); \
    GLD16(srcB + (size_t)offB1 + (KIDX), ldsc + (P)*24576 + 16384 + w*1024); \
} while (0)
#define LOAD_A(P) do { UNRL for (int f = 0; f < 4; ++f) { \
    af[f] = *(const i32x4*)(ldsc + (P)*24576 + wr*4096 + f*1024 + laneA); \
} } while (0)
#define LOAD_B(P) do { UNRL for (int e = 0; e < 4; ++e) { \
    bf[e] = *(const i32x4*)(ldsc + (P)*24576 + 8192 + wc*4096 + e*1024 + laneA); \
} } while (0)
#define MFMA_ALL() do { UNRL for (int f = 0; f < 4; ++f) UNRL for (int e = 0; e < 4; ++e) { \
    acc[f][e] = __builtin_amdgcn_mfma_i32_16x16x64_i8(af[f], bf[e], acc[f][e], 0, 0, 0); \
} } while (0)

#define TILE(P, PN, KTN) do { \
    STAGE(PN, KTN); \
    LOAD_A(P); LOAD_B(P); \
    PRIO1; MFMA_ALL(); PRIO0; \
    WAITV0(); BAR(); \
} while (0)

    // prologue: stage tile 0 (K bytes 0..63) into buf0, drain once
    STAGE(0, 0);
    WAITV0();
    BAR();

    for (int kt = 0; kt < K; kt += 128) {
        int kn1 = kt + 64;
        int kn2 = (kt + 128 < K) ? kt + 128 : 0;   // wrap: redundant, never read
        TILE(0, 1, kn1);
        TILE(1, 0, kn2);
    }

    // Coalesced epilogue (i32 -> float), per-wave 64x64 output.
    // Per-wave LDS region 16 x 68 floats (stride 272 B), base w*1088 floats
    // (8 x 4352 B = 34.8 KiB <= 48 KiB). Final TILE's BAR precedes.
    {
        int crowW = tm * 128 + wr * 64;
        int ccolW = tn * 256 + wc * 64;
        int lq = l >> 4, lc = l & 15;
        UNRL
        for (int fm = 0; fm < 4; ++fm) {
            UNRL
            for (int fn = 0; fn < 4; ++fn)
                UNRL
                for (int r = 0; r < 4; ++r)
                    ldsf[w * 1088 + (lq * 4 + r) * 68 + fn * 16 + lc]
                        = (float)acc[fm][fn][r];
            BAR();
            UNRL
            for (int rr = 0; rr < 4; ++rr) {
                f32x4 v = *(const f32x4*)&ldsf[w * 1088 + (rr * 4 + lq) * 68 + lc * 4];
                *(f32x4*)&C[(size_t)(crowW + fm * 16 + rr * 4 + lq) * N + (ccolW + lc * 4)] = v;
            }
            BAR();
        }
    }
}

// ---------------------------------------------------------------------------
// Kernel 6: per-row normalize in-place with row scale:
//   a = z*s_row + bq;  out = (a - mean) / (sqrt(var_ddof1) + eps)
// ---------------------------------------------------------------------------
__device__ __forceinline__ float block_sum_256(float v, float* red) {
    #pragma unroll
    for (int off = 32; off > 0; off >>= 1) v += __shfl_down(v, off, 64);
    int t = threadIdx.x;
    __syncthreads();
    if ((t & 63) == 0) red[t >> 6] = v;
    __syncthreads();
    return red[0] + red[1] + red[2] + red[3];
}

__global__ void rownorm_kernel(float* __restrict__ z, const float* __restrict__ bq,
                               const float* __restrict__ scale, int N) {
    __shared__ float red[4];
    int row = blockIdx.x;
    float* zr = z + (size_t)row * N;
    float srow = scale[row];
    int t = threadIdx.x;

    float4 v[4];
    float s = 0.f;
    #pragma unroll
    for (int j = 0; j < 4; ++j) {
        int idx = t + j * 256;
        float4 a = ((const float4*)zr)[idx];
        float4 bb = ((const float4*)bq)[idx];
        a.x = a.x * srow + bb.x; a.y = a.y * srow + bb.y;
        a.z = a.z * srow + bb.z; a.w = a.w * srow + bb.w;
        v[j] = a;
        s += (a.x + a.y) + (a.z + a.w);
    }
    float total = block_sum_256(s, red);
    float mean = total * (1.0f / 4096.0f);

    float q = 0.f;
    #pragma unroll
    for (int j = 0; j < 4; ++j) {
        float dx = v[j].x - mean, dy = v[j].y - mean, dz = v[j].z - mean, dw = v[j].w - mean;
        q += (dx * dx + dy * dy) + (dz * dz + dw * dw);
    }
    float qtot = block_sum_256(q, red);
    float var = qtot * (1.0f / 4095.0f);
    float inv = 1.0f / (sqrtf(var) + 1e-8f);

    #pragma unroll
    for (int j = 0; j < 4; ++j) {
        int idx = t + j * 256;
        float4 o;
        o.x = (v[j].x - mean) * inv;
        o.y = (v[j].y - mean) * inv;
        o.z = (v[j].z - mean) * inv;
        o.w = (v[j].w - mean) * inv;
        ((float4*)zr)[idx] = o;
    }
}

// ---------------------------------------------------------------------------
extern "C" void kernel_launch(void* const* d_in, const int* in_sizes, int n_in,
                              void* d_out, int out_size, void* d_ws, size_t ws_size,
                              hipStream_t stream) {
    const float* x = (const float*)d_in[0];
    const float* W = (const float*)d_in[1];
    const float* b = (const float*)d_in[2];
    float* out = (float*)d_out;

    const int N = in_sizes[2];            // 4096 (OUT)
    const int K = in_sizes[1] / N;        // 4096 (IN)
    const int M = in_sizes[0] / K;        // 8192

    // workspace layout
    char* ws = (char*)d_ws;
    i8_t* xq = (i8_t*)ws;                                           // M*K i8
    i8_t* wq = (i8_t*)(ws + (size_t)M * K);                         // N*K i8
    float* scales = (float*)(ws + (size_t)M * K + (size_t)N * K);   // M fp32
    float* bq = (float*)(ws + (size_t)M * K + (size_t)N * K + (size_t)M * 4);  // N fp32
    double* sumw = (double*)(ws + (size_t)M * K + (size_t)N * K + (size_t)M * 4 + (size_t)N * 4);

    hipMemsetAsync(sumw, 0, sizeof(double), stream);
    sum_w_kernel<<<1024, 256, 0, stream>>>(W, sumw, N * K / 4);
    quant_w_kernel<<<2048, 256, 0, stream>>>(W, wq, sumw, 1.0f / (float)((size_t)N * K), N * K / 4);
    quant_x_kernel<<<M, 256, 0, stream>>>(x, xq, scales, K);
    quant_b_kernel<<<1, 256, 0, stream>>>(b, bq, N);

    int grid = (M / 128) * (N / 256);
    gemm_i8_128x256<<<grid, 512, 0, stream>>>(xq, wq, out, M, N, K);

    rownorm_kernel<<<M, 256, 0, stream>>>(out, bq, scales, N);
}

// Round 15
// 235.360 us; speedup vs baseline: 5.6366x; 1.0839x over previous
//
#include <hip/hip_runtime.h>
#include <hip/hip_bf16.h>

typedef signed char i8_t;
typedef int i32x4 __attribute__((ext_vector_type(4)));
typedef float f32x4 __attribute__((ext_vector_type(4)));

typedef const __attribute__((address_space(1))) void* gptr_t;
typedef __attribute__((address_space(3))) void* sptr_t;

#define GLD16(g, l) __builtin_amdgcn_global_load_lds((gptr_t)(g), (sptr_t)(l), 16, 0, 0)

// ---------------------------------------------------------------------------
// Kernel 1: global sum of W (fp32 partials, double atomic) -> ws scalar
// ---------------------------------------------------------------------------
__global__ void sum_w_kernel(const float* __restrict__ W, double* __restrict__ out, int n4) {
    int i = blockIdx.x * blockDim.x + threadIdx.x;
    int stride = gridDim.x * blockDim.x;
    float s = 0.f;
    for (; i < n4; i += stride) {
        float4 v = ((const float4*)W)[i];
        s += (v.x + v.y) + (v.z + v.w);
    }
    #pragma unroll
    for (int off = 32; off > 0; off >>= 1) s += __shfl_down(s, off, 64);
    __shared__ float red[4];
    int t = threadIdx.x;
    if ((t & 63) == 0) red[t >> 6] = s;
    __syncthreads();
    if (t == 0) {
        float bs = red[0] + red[1] + red[2] + red[3];
        atomicAdd(out, (double)bs);
    }
}

// ---------------------------------------------------------------------------
// Kernel 2: quantize W -> i8 {0,1}
// ---------------------------------------------------------------------------
__global__ void quant_w_kernel(const float* __restrict__ W, i8_t* __restrict__ Wq,
                               const double* __restrict__ sumw, float inv_n, int n4) {
    float mean = (float)(*sumw) * inv_n;
    int i = blockIdx.x * blockDim.x + threadIdx.x;
    int stride = gridDim.x * blockDim.x;
    for (; i < n4; i += stride) {
        float4 v = ((const float4*)W)[i];
        char4 o;
        o.x = (v.x > mean) ? 1 : 0;
        o.y = (v.y > mean) ? 1 : 0;
        o.z = (v.z > mean) ? 1 : 0;
        o.w = (v.w > mean) ? 1 : 0;
        ((char4*)Wq)[i] = o;
    }
}

// ---------------------------------------------------------------------------
// Kernel 3: per-row symmetric int8 quantization of x (one block per row).
// s_row = absmax/127; xq = rint(x/s) clamped; scale[row] = s_row.
// ---------------------------------------------------------------------------
__global__ void quant_x_kernel(const float* __restrict__ x, i8_t* __restrict__ xq,
                               float* __restrict__ scale, int K) {
    __shared__ float red[4];
    int row = blockIdx.x;
    int t = threadIdx.x;
    const float4* xr = (const float4*)(x + (size_t)row * K);

    float4 v[4];
    float am = 0.f;
    #pragma unroll
    for (int j = 0; j < 4; ++j) {
        v[j] = xr[t + j * 256];
        am = fmaxf(am, fmaxf(fmaxf(fabsf(v[j].x), fabsf(v[j].y)),
                             fmaxf(fabsf(v[j].z), fabsf(v[j].w))));
    }
    #pragma unroll
    for (int off = 32; off > 0; off >>= 1) am = fmaxf(am, __shfl_down(am, off, 64));
    if ((t & 63) == 0) red[t >> 6] = am;
    __syncthreads();
    float amax = fmaxf(fmaxf(red[0], red[1]), fmaxf(red[2], red[3]));
    amax = fmaxf(amax, 1e-20f);
    float s = amax * (1.0f / 127.0f);
    float inv = 127.0f / amax;
    if (t == 0) scale[row] = s;

    char4* oq = (char4*)(xq + (size_t)row * K);
    #pragma unroll
    for (int j = 0; j < 4; ++j) {
        char4 o;
        o.x = (i8_t)(int)rintf(fminf(fmaxf(v[j].x * inv, -127.f), 127.f));
        o.y = (i8_t)(int)rintf(fminf(fmaxf(v[j].y * inv, -127.f), 127.f));
        o.z = (i8_t)(int)rintf(fminf(fmaxf(v[j].z * inv, -127.f), 127.f));
        o.w = (i8_t)(int)rintf(fminf(fmaxf(v[j].w * inv, -127.f), 127.f));
        oq[t + j * 256] = o;
    }
}

// ---------------------------------------------------------------------------
// Kernel 4: quantize b (single block; n = 4096)
// ---------------------------------------------------------------------------
__global__ void quant_b_kernel(const float* __restrict__ b, float* __restrict__ bq, int n) {
    int t = threadIdx.x;
    float s = 0.f;
    for (int i = t; i < n; i += 256) s += b[i];
    #pragma unroll
    for (int off = 32; off > 0; off >>= 1) s += __shfl_down(s, off, 64);
    __shared__ float red[4];
    if ((t & 63) == 0) red[t >> 6] = s;
    __syncthreads();
    float mean = (red[0] + red[1] + red[2] + red[3]) / (float)n;
    for (int i = t; i < n; i += 256) bq[i] = (b[i] > mean) ? 1.0f : 0.0f;
}

// ---------------------------------------------------------------------------
// Kernel 5: INT8 MFMA GEMM, 256x256 tile, BK=128 (i8), 8 waves (2Mx4N).
// R15: R12's proven kernel (125us) with sync points HALVED: 2 phases/tile
// (4 barriers -> 2), two counted vmcnt(4) gates. Gate arithmetic (verified):
// at each gate in-flight = 8; vmcnt(4) forces exactly the older phase-pair's
// 4 loads, issued ~1 full phase (~3500 cyc) earlier >> 900-cyc HBM latency
// -> free. Publications precede reads: A0',B0' forced at ph2-end gate,
// consumed next ph1 (after BAR); B1',A1' forced at ph1-end gate, consumed
// ph2 (after BAR). Register liveness: Q01 ordered BEFORE the A1 reload so
// the single af[] set works (R12's pattern, de-barriered).
//   C[M,N] = (float)( A_i8[M,K] * B_i8[N,K]^T )  (scale re-applied in rownorm)
// MFMA v_mfma_i32_16x16x64_i8: lane group g=(l>>4) holds k=g*16+[0,16);
// laneA1=^64 covers K bytes 64..127.
// LDS swizzle (full-granule): byte ^= ((byte>>3) & 0x70) — 0 conflicts (R3).
// Epilogue: i32->float, coalesced LDS bounce (f32x4 stores, 256B segments).
// ---------------------------------------------------------------------------
#define PRIO1 __builtin_amdgcn_s_setprio(1)
#define PRIO0 __builtin_amdgcn_s_setprio(0)
#define BAR() __builtin_amdgcn_s_barrier()
#define WAITV4() asm volatile("s_waitcnt vmcnt(4)" ::: "memory")
#define WAITV0() asm volatile("s_waitcnt vmcnt(0)" ::: "memory")
#define UNRL _Pragma("unroll")

__global__ __launch_bounds__(512, 2) void gemm_i8_256(
        const i8_t* __restrict__ A, const i8_t* __restrict__ B,
        float* __restrict__ C, int M, int N, int K) {
    __shared__ int lds32[32768];       // 128 KiB: [buf][A 32K i8 | B 32K i8]
    char* ldsc = (char*)lds32;
    float* ldsf = (float*)lds32;       // epilogue bounce reuses the same LDS

    int nbn = N >> 8;
    int nwg = gridDim.x;
    int bid = blockIdx.x;
    int cpx = nwg >> 3;
    int wg = (bid & 7) * cpx + (bid >> 3);   // XCD swizzle (nwg % 8 == 0)
    int tm = wg / nbn, tn = wg % nbn;

    int t = threadIdx.x;
    int w = t >> 6, l = t & 63;
    int wr = w >> 2, wc = w & 3;             // 2 M-waves x 4 N-waves
    int wrOff = wr * 8192;                   // 64 rows * 128 B
    int wcOff = wc * 4096;                   // 32 rows * 128 B

    // read-side lane offsets (bytes), full-granule swizzle folded in
    int baseL = ((l & 15) * 128) + ((l >> 4) * 16);
    int laneA0 = baseL ^ ((l & 7) << 4);     // K bytes 0..63
    int laneA1 = laneA0 ^ 64;                // K bytes 64..127

    // stage-side source offsets (i8 elems == bytes), inverse swizzle
    int offA[2][2], offB[2][2];
    UNRL
    for (int c = 0; c < 2; ++c) {
        int o = (t + c * 512) * 16;
        int os = o ^ ((o >> 3) & 0x70);
        int lr = os >> 7;
        int col = os & 127;
        UNRL
        for (int h = 0; h < 2; ++h) {
            offA[c][h] = ((lr >> 6) * 128 + h * 64 + (lr & 63)) * K + col;
            offB[c][h] = ((lr >> 5) * 64 + h * 32 + (lr & 31)) * K + col;
        }
    }

    const i8_t* srcA = A + (size_t)tm * 256 * K;
    const i8_t* srcB = B + (size_t)tn * 256 * K;

    i32x4 acc[8][4] = {};
    i32x4 af[4][2], bf0[2][2], bf1[2][2];

#define STAGE_A(P, H, KIDX) do { \
    GLD16(srcA + (size_t)offA[0][H] + (KIDX), ldsc + (P)*65536 + (H)*16384 + w*1024); \
    GLD16(srcA + (size_t)offA[1][H] + (KIDX), ldsc + (P)*65536 + (H)*16384 + 8192 + w*1024); \
} while (0)
#define STAGE_B(P, H, KIDX) do { \
    GLD16(srcB + (size_t)offB[0][H] + (KIDX), ldsc + (P)*65536 + 32768 + (H)*16384 + w*1024); \
    GLD16(srcB + (size_t)offB[1][H] + (KIDX), ldsc + (P)*65536 + 32768 + (H)*16384 + 8192 + w*1024); \
} while (0)
#define LOAD_AF(P, H) do { UNRL for (int f = 0; f < 4; ++f) { \
    af[f][0] = *(const i32x4*)(ldsc + (P)*65536 + (H)*16384 + wrOff + f*2048 + laneA0); \
    af[f][1] = *(const i32x4*)(ldsc + (P)*65536 + (H)*16384 + wrOff + f*2048 + laneA1); \
} } while (0)
#define LOAD_BF(BF, P, H) do { UNRL for (int e = 0; e < 2; ++e) { \
    BF[e][0] = *(const i32x4*)(ldsc + (P)*65536 + 32768 + (H)*16384 + wcOff + e*2048 + laneA0); \
    BF[e][1] = *(const i32x4*)(ldsc + (P)*65536 + 32768 + (H)*16384 + wcOff + e*2048 + laneA1); \
} } while (0)
#define MFMA_Q(QM, QN, BF) do { UNRL for (int f = 0; f < 4; ++f) UNRL for (int e = 0; e < 2; ++e) { \
    acc[(QM)*4+f][(QN)*2+e] = __builtin_amdgcn_mfma_i32_16x16x64_i8(af[f][0], BF[e][0], acc[(QM)*4+f][(QN)*2+e], 0, 0, 0); \
    acc[(QM)*4+f][(QN)*2+e] = __builtin_amdgcn_mfma_i32_16x16x64_i8(af[f][1], BF[e][1], acc[(QM)*4+f][(QN)*2+e], 0, 0, 0); \
} } while (0)

// 2-phase tile: ph1 = {read A0,B0 | stage A0',B0' | Q00 | gate | BAR},
// ph2 = {read B1 | stage B1' | Q01 | read A1 | stage A1' | Q11,Q10 | gate | BAR}
#define TILE(P, PN, KTN) do { \
    LOAD_AF(P, 0); LOAD_BF(bf0, P, 0); STAGE_A(PN, 0, KTN); STAGE_B(PN, 0, KTN); \
    PRIO1; MFMA_Q(0, 0, bf0); PRIO0; WAITV4(); BAR(); \
    LOAD_BF(bf1, P, 1);                STAGE_B(PN, 1, KTN); \
    PRIO1; MFMA_Q(0, 1, bf1); PRIO0; \
    LOAD_AF(P, 1);                     STAGE_A(PN, 1, KTN); \
    PRIO1; MFMA_Q(1, 1, bf1); MFMA_Q(1, 0, bf0); PRIO0; WAITV4(); BAR(); \
} while (0)

    // prologue: stage tile 0 (K 0..127) into buf0, drain once
    STAGE_A(0, 0, 0); STAGE_B(0, 0, 0); STAGE_B(0, 1, 0); STAGE_A(0, 1, 0);
    WAITV0();
    BAR();

    for (int kt = 0; kt < K; kt += 256) {
        int kn1 = kt + 128;
        int kn2 = (kt + 256 < K) ? kt + 256 : 0;   // wrap: redundant, never read
        TILE(0, 1, kn1);
        TILE(1, 0, kn2);
    }

    WAITV0();  // drain trailing stages (incl. wrapped GLD16 into the buffers)
    BAR();     // all waves' LDS writes retired before bounce reuse

    // Coalesced epilogue (i32 -> float). Frag layout: (fm,fn,r) at
    // row = wr*128 + fm*16 + (l>>4)*4 + r, col = wc*64 + fn*16 + (l&15).
    {
        int crowW = tm * 256 + wr * 128;
        int ccolW = tn * 256 + wc * 64;
        int lq = l >> 4, lc = l & 15;
        UNRL
        for (int c = 0; c < 4; ++c) {
            UNRL
            for (int fi = 0; fi < 2; ++fi) {
                int fm = c * 2 + fi;
                UNRL
                for (int fn = 0; fn < 4; ++fn)
                    UNRL
                    for (int r = 0; r < 4; ++r)
                        ldsf[w * 2176 + (fi * 16 + lq * 4 + r) * 68 + fn * 16 + lc]
                            = (float)acc[fm][fn][r];
            }
            BAR();
            UNRL
            for (int rr = 0; rr < 8; ++rr) {
                f32x4 v = *(const f32x4*)&ldsf[w * 2176 + (rr * 4 + lq) * 68 + lc * 4];
                *(f32x4*)&C[(size_t)(crowW + c * 32 + rr * 4 + lq) * N + (ccolW + lc * 4)] = v;
            }
            BAR();
        }
    }
}

// ---------------------------------------------------------------------------
// Kernel 6: per-row normalize in-place with row scale:
//   a = z*s_row + bq;  out = (a - mean) / (sqrt(var_ddof1) + eps)
// ---------------------------------------------------------------------------
__device__ __forceinline__ float block_sum_256(float v, float* red) {
    #pragma unroll
    for (int off = 32; off > 0; off >>= 1) v += __shfl_down(v, off, 64);
    int t = threadIdx.x;
    __syncthreads();
    if ((t & 63) == 0) red[t >> 6] = v;
    __syncthreads();
    return red[0] + red[1] + red[2] + red[3];
}

__global__ void rownorm_kernel(float* __restrict__ z, const float* __restrict__ bq,
                               const float* __restrict__ scale, int N) {
    __shared__ float red[4];
    int row = blockIdx.x;
    float* zr = z + (size_t)row * N;
    float srow = scale[row];
    int t = threadIdx.x;

    float4 v[4];
    float s = 0.f;
    #pragma unroll
    for (int j = 0; j < 4; ++j) {
        int idx = t + j * 256;
        float4 a = ((const float4*)zr)[idx];
        float4 bb = ((const float4*)bq)[idx];
        a.x = a.x * srow + bb.x; a.y = a.y * srow + bb.y;
        a.z = a.z * srow + bb.z; a.w = a.w * srow + bb.w;
        v[j] = a;
        s += (a.x + a.y) + (a.z + a.w);
    }
    float total = block_sum_256(s, red);
    float mean = total * (1.0f / 4096.0f);

    float q = 0.f;
    #pragma unroll
    for (int j = 0; j < 4; ++j) {
        float dx = v[j].x - mean, dy = v[j].y - mean, dz = v[j].z - mean, dw = v[j].w - mean;
        q += (dx * dx + dy * dy) + (dz * dz + dw * dw);
    }
    float qtot = block_sum_256(q, red);
    float var = qtot * (1.0f / 4095.0f);
    float inv = 1.0f / (sqrtf(var) + 1e-8f);

    #pragma unroll
    for (int j = 0; j < 4; ++j) {
        int idx = t + j * 256;
        float4 o;
        o.x = (v[j].x - mean) * inv;
        o.y = (v[j].y - mean) * inv;
        o.z = (v[j].z - mean) * inv;
        o.w = (v[j].w - mean) * inv;
        ((float4*)zr)[idx] = o;
    }
}

// ---------------------------------------------------------------------------
extern "C" void kernel_launch(void* const* d_in, const int* in_sizes, int n_in,
                              void* d_out, int out_size, void* d_ws, size_t ws_size,
                              hipStream_t stream) {
    const float* x = (const float*)d_in[0];
    const float* W = (const float*)d_in[1];
    const float* b = (const float*)d_in[2];
    float* out = (float*)d_out;

    const int N = in_sizes[2];            // 4096 (OUT)
    const int K = in_sizes[1] / N;        // 4096 (IN)
    const int M = in_sizes[0] / K;        // 8192

    // workspace layout
    char* ws = (char*)d_ws;
    i8_t* xq = (i8_t*)ws;                                           // M*K i8
    i8_t* wq = (i8_t*)(ws + (size_t)M * K);                         // N*K i8
    float* scales = (float*)(ws + (size_t)M * K + (size_t)N * K);   // M fp32
    float* bq = (float*)(ws + (size_t)M * K + (size_t)N * K + (size_t)M * 4);  // N fp32
    double* sumw = (double*)(ws + (size_t)M * K + (size_t)N * K + (size_t)M * 4 + (size_t)N * 4);

    hipMemsetAsync(sumw, 0, sizeof(double), stream);
    sum_w_kernel<<<1024, 256, 0, stream>>>(W, sumw, N * K / 4);
    quant_w_kernel<<<2048, 256, 0, stream>>>(W, wq, sumw, 1.0f / (float)((size_t)N * K), N * K / 4);
    quant_x_kernel<<<M, 256, 0, stream>>>(x, xq, scales, K);
    quant_b_kernel<<<1, 256, 0, stream>>>(b, bq, N);

    int grid = (M / 256) * (N / 256);
    gemm_i8_256<<<grid, 512, 0, stream>>>(xq, wq, out, M, N, K);

    rownorm_kernel<<<M, 256, 0, stream>>>(out, bq, scales, N);
}